// Round 8
// baseline (251.306 us; speedup 1.0000x reference)
//
#include <hip/hip_runtime.h>
#include <math.h>

#define BB 4
#define LL 512
#define DD 256
#define HH 8
#define DHH 32
#define NB 12  // BUCKETS + 1 (row 11 is the zero padding row)

// Kernel 1: Q,K,V projections. Block = (mat, 8 rows), 256 thr; thread = 2 rows x 4 cols.
// 768 blocks -> 3 blocks/CU (12 waves/CU). K written transposed KT[b][h][d][k].
__global__ __launch_bounds__(256) void qkv_kernel(const float* __restrict__ x,
    const float* __restrict__ Wq, const float* __restrict__ bq,
    const float* __restrict__ Wk, const float* __restrict__ bk,
    const float* __restrict__ Wv, const float* __restrict__ bv,
    float* __restrict__ Q, float* __restrict__ KT, float* __restrict__ V) {
    __shared__ float xs[8][DD];
    const int mat = blockIdx.x >> 8;          // 0=Q, 1=K, 2=V (256 tiles each)
    const int r0 = (blockIdx.x & 255) * 8;    // 8-row tile over 2048 rows
    const int t = threadIdx.x;
    const int cg = t & 63, rg = t >> 6;       // col group (x4), row group (x2)
    const int c0 = cg * 4;
    {   // stage 8 rows of x (512 float4, 2/thread, coalesced)
        const float4* xg = (const float4*)(x + r0 * DD);
        float4* xsv = (float4*)&xs[0][0];
        xsv[t] = xg[t];
        xsv[t + 256] = xg[t + 256];
    }
    __syncthreads();
    const float* W    = (mat == 0) ? Wq : (mat == 1) ? Wk : Wv;
    const float* bias = (mat == 0) ? bq : (mat == 1) ? bk : bv;
    float acc[2][4];
#pragma unroll
    for (int r = 0; r < 2; ++r)
#pragma unroll
        for (int c = 0; c < 4; ++c) acc[r][c] = bias[c0 + c];
    for (int i0 = 0; i0 < DD; i0 += 4) {
        float4 wv4[4], xv4[2];
#pragma unroll
        for (int j = 0; j < 4; ++j) wv4[j] = *(const float4*)&W[(i0 + j) * DD + c0];
#pragma unroll
        for (int r = 0; r < 2; ++r) xv4[r] = *(const float4*)&xs[rg * 2 + r][i0];
        const float* wf = (const float*)wv4;  // wf[j*4+c]
        const float* xf = (const float*)xv4;  // xf[r*4+j]
#pragma unroll
        for (int r = 0; r < 2; ++r)
#pragma unroll
            for (int j = 0; j < 4; ++j)
#pragma unroll
                for (int c = 0; c < 4; ++c)
                    acc[r][c] = fmaf(xf[r * 4 + j], wf[j * 4 + c], acc[r][c]);
    }
    if (mat == 0) {
        const float s = 0.17677669529663687f;  // 1/sqrt(DH)
#pragma unroll
        for (int r = 0; r < 2; ++r) {
            float4 o = make_float4(acc[r][0] * s, acc[r][1] * s, acc[r][2] * s, acc[r][3] * s);
            *(float4*)&Q[(r0 + rg * 2 + r) * DD + c0] = o;
        }
    } else if (mat == 1) {
        const int b = r0 >> 9;                 // tiles never straddle batches
        const int kb = (r0 & 511) + rg * 2;    // 2 consecutive k
#pragma unroll
        for (int c = 0; c < 4; ++c) {
            const int col = c0 + c;
            const int h = col >> 5, dd = col & 31;
            float* p = KT + ((long)((b * HH + h) * DHH + dd)) * LL + kb;
            p[0] = acc[0][c];
            p[1] = acc[1][c];
        }
    } else {
#pragma unroll
        for (int r = 0; r < 2; ++r) {
            float4 o = make_float4(acc[r][0], acc[r][1], acc[r][2], acc[r][3]);
            *(float4*)&V[(r0 + rg * 2 + r) * DD + c0] = o;
        }
    }
}

// Kernel 2: fused rel-P + scores + softmax. Block = (b, 16-q tile, h), 512 threads.
// Thread t owns column k=t; the 32-reg K fragment (coalesced from KT) is loaded ONCE
// and reused across two 8-row passes. No max-subtraction (scores bounded ~±1; masked
// lanes e=0 exactly). All LDS handoffs write-all -> barrier -> read (deterministic).
__global__ __launch_bounds__(512) void scores_kernel(const float* __restrict__ Q,
    const float* __restrict__ KT, const float* __restrict__ uvec,
    const float* __restrict__ vvec, const float* __restrict__ rel_table,
    const int* __restrict__ mask, const int* __restrict__ dist,
    float* __restrict__ attn) {
    __shared__ float Qu[16][DHH];       // q + u
    __shared__ float Qv8[16][DHH];      // q + v
    __shared__ float rels[NB][DHH + 1]; // head slice of rel_table, padded
    __shared__ float Ps[16][NB];
    __shared__ float wsum[8][8];        // [row-in-pass][wave]
    const int blk = blockIdx.x;         // ((b*32 + qt)*8 + h)
    const int h = blk & 7;
    const int rest = blk >> 3;
    const int qt = rest & 31;
    const int b = rest >> 5;
    const int q0 = qt * 16;
    const int t = threadIdx.x;          // k index 0..511
    const int w = t >> 6, l = t & 63;

    {                                   // stage Q(+u), Q(+v): 16 rows x 32 cols = all 512 thr
        const int r = t >> 5, c = t & 31;
        const float qv = Q[(b * LL + q0 + r) * DD + h * DHH + c];
        Qu[r][c]  = qv + uvec[h * DHH + c];
        Qv8[r][c] = qv + vvec[h * DHH + c];
    }
    if (t < NB * DHH) {                 // stage rel_table head slice: 12 x 32
        rels[t >> 5][t & 31] = rel_table[(t >> 5) * DD + h * DHH + (t & 31)];
    }
    __syncthreads();
    if (t < 16 * NB) {                  // Ps[r][bk] = dot32(Qv8[r], rels[bk])
        const int bk = t >> 4, r = t & 15;
        float a = 0.f;
#pragma unroll
        for (int d = 0; d < DHH; ++d) a = fmaf(Qv8[r][d], rels[bk][d], a);
        Ps[r][bk] = a;
    }
    __syncthreads();

    float kd[DHH];                      // K column k=t (lane-coalesced), loaded ONCE
    const float* ktp = KT + (long)(b * HH + h) * DHH * LL + t;
#pragma unroll
    for (int j = 0; j < DHH; ++j) kd[j] = ktp[(long)j * LL];

#pragma unroll
    for (int p = 0; p < 2; ++p) {       // two 8-row passes sharing kd
        const int qb = q0 + p * 8;
        int dv[8], mv[8];
#pragma unroll
        for (int r = 0; r < 8; ++r) {
            const int mq = (b * LL + qb + r) * LL + t;
            dv[r] = dist[mq];
            mv[r] = mask[mq];
        }
        float e[8];
#pragma unroll
        for (int r = 0; r < 8; ++r) {
            float acc = Ps[p * 8 + r][dv[r]];
            const float4* qup = (const float4*)&Qu[p * 8 + r][0];
#pragma unroll
            for (int j = 0; j < 8; ++j) {
                const float4 qq = qup[j];
                acc = fmaf(qq.x, kd[4 * j + 0], acc);
                acc = fmaf(qq.y, kd[4 * j + 1], acc);
                acc = fmaf(qq.z, kd[4 * j + 2], acc);
                acc = fmaf(qq.w, kd[4 * j + 3], acc);
            }
            e[r] = mv[r] ? 0.f : __expf(acc);
        }
        float sm[8];
#pragma unroll
        for (int r = 0; r < 8; ++r) {
            float s = e[r];
            for (int off = 32; off > 0; off >>= 1) s += __shfl_xor(s, off);
            sm[r] = s;
        }
        if (p) __syncthreads();         // WAR: pass-0 readers done before rewrite
        if (l == 0) {
#pragma unroll
            for (int r = 0; r < 8; ++r) wsum[r][w] = sm[r];
        }
        __syncthreads();
#pragma unroll
        for (int r = 0; r < 8; ++r) {
            float tot = wsum[r][0];
#pragma unroll
            for (int i = 1; i < 8; ++i) tot += wsum[r][i];
            attn[((long)(b * HH + h) * LL + qb + r) * LL + t] = e[r] * (1.0f / tot);
        }
    }
}

// Kernel 3: fused ctx + output projection. Block = (b, 4 q rows), 512 blocks.
// Thread = (q, d4): wave w == q row, so attn loads are WAVE-UNIFORM (1 line / 64
// lanes); V loads are float4 coalesced (64 lanes x 16B contiguous). Projection:
// Wo float4 coalesced, Cs via uniform LDS broadcast.
__global__ __launch_bounds__(256) void ctx_out_kernel(const float* __restrict__ attn,
    const float* __restrict__ V, const float* __restrict__ Wo,
    const float* __restrict__ bo, float* __restrict__ out) {
    __shared__ float Cs[4][DD];
    const int blk = blockIdx.x;          // b*128 + qt
    const int b = blk >> 7;
    const int q0 = (blk & 127) * 4;
    const int t = threadIdx.x;
    const int q = t >> 6;                // wave index == q row
    const int d0 = (t & 63) * 4;
    const int h = d0 >> 5;
    const float* vb = V + b * LL * DD + d0;
    const float* ap = attn + ((long)(b * HH + h) * LL + q0 + q) * LL;
    float4 accA = make_float4(0.f, 0.f, 0.f, 0.f);
    float4 accB = make_float4(0.f, 0.f, 0.f, 0.f);
    for (int k0 = 0; k0 < LL; k0 += 8) {
        const float4 a0 = *(const float4*)&ap[k0];       // wave-uniform
        const float4 a1 = *(const float4*)&ap[k0 + 4];
        float4 v[8];
#pragma unroll
        for (int j = 0; j < 8; ++j) v[j] = *(const float4*)&vb[(k0 + j) * DD];
#pragma unroll
        for (int cc = 0; cc < 4; ++cc) {
            const float* af = (const float*)&a0;
            const float* bf = (const float*)&a1;
            accA.x = fmaf(af[cc], ((const float*)&v[cc])[0], accA.x);
            accA.y = fmaf(af[cc], ((const float*)&v[cc])[1], accA.y);
            accA.z = fmaf(af[cc], ((const float*)&v[cc])[2], accA.z);
            accA.w = fmaf(af[cc], ((const float*)&v[cc])[3], accA.w);
            accB.x = fmaf(bf[cc], ((const float*)&v[cc + 4])[0], accB.x);
            accB.y = fmaf(bf[cc], ((const float*)&v[cc + 4])[1], accB.y);
            accB.z = fmaf(bf[cc], ((const float*)&v[cc + 4])[2], accB.z);
            accB.w = fmaf(bf[cc], ((const float*)&v[cc + 4])[3], accB.w);
        }
    }
    float4 cr = make_float4(accA.x + accB.x, accA.y + accB.y,
                            accA.z + accB.z, accA.w + accB.w);
    *(float4*)&Cs[q][d0] = cr;
    __syncthreads();
    float4 o = *(const float4*)&bo[d0];
    for (int i0 = 0; i0 < DD; i0 += 4) {
        const float4 cv = *(const float4*)&Cs[q][i0];    // uniform LDS broadcast
        float4 wr[4];
#pragma unroll
        for (int j = 0; j < 4; ++j) wr[j] = *(const float4*)&Wo[(i0 + j) * DD + d0];
        const float* cf = (const float*)&cv;
#pragma unroll
        for (int j = 0; j < 4; ++j) {
            o.x = fmaf(cf[j], wr[j].x, o.x);
            o.y = fmaf(cf[j], wr[j].y, o.y);
            o.z = fmaf(cf[j], wr[j].z, o.z);
            o.w = fmaf(cf[j], wr[j].w, o.w);
        }
    }
    *(float4*)&out[(b * LL + q0 + q) * DD + d0] = o;
}

extern "C" void kernel_launch(void* const* d_in, const int* in_sizes, int n_in,
                              void* d_out, int out_size, void* d_ws, size_t ws_size,
                              hipStream_t stream) {
    const float* x    = (const float*)d_in[0];
    const int* mk     = (const int*)d_in[1];   // jax bool -> int32
    const int* dist   = (const int*)d_in[2];
    const float* Wq = (const float*)d_in[3];
    const float* bq = (const float*)d_in[4];
    const float* Wk = (const float*)d_in[5];
    const float* bk = (const float*)d_in[6];
    const float* Wv = (const float*)d_in[7];
    const float* bv = (const float*)d_in[8];
    const float* Wo = (const float*)d_in[9];
    const float* bo = (const float*)d_in[10];
    const float* rel_table = (const float*)d_in[11];
    const float* uvec = (const float*)d_in[12];
    const float* vvec = (const float*)d_in[13];

    float* out  = (float*)d_out;                 // (B,L,D)
    float* attn = out + BB * LL * DD;            // (B,H,L,L)

    float* Q  = (float*)d_ws;
    float* KT = Q + BB * LL * DD;                // K transposed: [B][H][DH][L]
    float* V  = KT + BB * LL * DD;               // [B][L][D]; 6 MB ws total

    qkv_kernel<<<3 * 256, 256, 0, stream>>>(x, Wq, bq, Wk, bk, Wv, bv, Q, KT, V);
    scores_kernel<<<BB * (LL / 16) * HH, 512, 0, stream>>>(Q, KT, uvec, vvec, rel_table,
                                                           mk, dist, attn);
    ctx_out_kernel<<<BB * (LL / 4), 256, 0, stream>>>(attn, V, Wo, bo, out);
}

// Round 9
// 191.164 us; speedup vs baseline: 1.3146x; 1.3146x over previous
//
#include <hip/hip_runtime.h>
#include <math.h>

#define BB 4
#define LL 512
#define DD 256
#define HH 8
#define DHH 32
#define NB 12  // BUCKETS + 1 (row 11 is the zero padding row)

// K1: QKV projections. Block = (mat, 8 rows), 256 thr; thread = 2 rows x 4 cols.
// mat0 writes Qu = q/sqrt(dh)+u and Qv = q/sqrt(dh)+v (u,v baked in).
// mat1 writes KT[b][h][d][k] (k contiguous). mat2 writes V[b][k][d].
__global__ __launch_bounds__(256) void qkv_kernel(const float* __restrict__ x,
    const float* __restrict__ Wq, const float* __restrict__ bq,
    const float* __restrict__ Wk, const float* __restrict__ bk,
    const float* __restrict__ Wv, const float* __restrict__ bv,
    const float* __restrict__ uvec, const float* __restrict__ vvec,
    float* __restrict__ Qu, float* __restrict__ Qv,
    float* __restrict__ KT, float* __restrict__ V) {
    __shared__ float xs[8][DD];
    const int mat = blockIdx.x >> 8;          // 0=Q, 1=K, 2=V
    const int r0 = (blockIdx.x & 255) * 8;
    const int t = threadIdx.x;
    const int cg = t & 63, rg = t >> 6;
    const int c0 = cg * 4;
    {
        const float4* xg = (const float4*)(x + r0 * DD);
        float4* xsv = (float4*)&xs[0][0];
        xsv[t] = xg[t];
        xsv[t + 256] = xg[t + 256];
    }
    __syncthreads();
    const float* W    = (mat == 0) ? Wq : (mat == 1) ? Wk : Wv;
    const float* bias = (mat == 0) ? bq : (mat == 1) ? bk : bv;
    float acc[2][4];
#pragma unroll
    for (int r = 0; r < 2; ++r)
#pragma unroll
        for (int c = 0; c < 4; ++c) acc[r][c] = bias[c0 + c];
    for (int i0 = 0; i0 < DD; i0 += 4) {
        float4 wv4[4], xv4[2];
#pragma unroll
        for (int j = 0; j < 4; ++j) wv4[j] = *(const float4*)&W[(i0 + j) * DD + c0];
#pragma unroll
        for (int r = 0; r < 2; ++r) xv4[r] = *(const float4*)&xs[rg * 2 + r][i0];
        const float* wf = (const float*)wv4;
        const float* xf = (const float*)xv4;
#pragma unroll
        for (int r = 0; r < 2; ++r)
#pragma unroll
            for (int j = 0; j < 4; ++j)
#pragma unroll
                for (int c = 0; c < 4; ++c)
                    acc[r][c] = fmaf(xf[r * 4 + j], wf[j * 4 + c], acc[r][c]);
    }
    if (mat == 0) {
        const float s = 0.17677669529663687f;  // 1/sqrt(DH)
        const float4 u4 = *(const float4*)&uvec[c0];
        const float4 v4 = *(const float4*)&vvec[c0];
#pragma unroll
        for (int r = 0; r < 2; ++r) {
            const int row = r0 + rg * 2 + r;
            float4 q = make_float4(acc[r][0] * s, acc[r][1] * s, acc[r][2] * s, acc[r][3] * s);
            *(float4*)&Qu[row * DD + c0] = make_float4(q.x + u4.x, q.y + u4.y, q.z + u4.z, q.w + u4.w);
            *(float4*)&Qv[row * DD + c0] = make_float4(q.x + v4.x, q.y + v4.y, q.z + v4.z, q.w + v4.w);
        }
    } else if (mat == 1) {
        const int b = r0 >> 9;
        const int kb = (r0 & 511) + rg * 2;
#pragma unroll
        for (int c = 0; c < 4; ++c) {
            const int col = c0 + c;
            const int h = col >> 5, dd = col & 31;
            float* p = KT + ((long)((b * HH + h) * DHH + dd)) * LL + kb;
            p[0] = acc[0][c];
            p[1] = acc[1][c];
        }
    } else {
#pragma unroll
        for (int r = 0; r < 2; ++r)
            *(float4*)&V[(r0 + rg * 2 + r) * DD + c0] =
                make_float4(acc[r][0], acc[r][1], acc[r][2], acc[r][3]);
    }
}

// K2: P[b,h,q,t] = dot32(Qv[b,q,h], rel_table[t,h]). Tiny (196K dot-32s).
__global__ void relp_kernel(const float* __restrict__ Qv, const float* __restrict__ rel_table,
                            float* __restrict__ P) {
    const int idx = blockIdx.x * blockDim.x + threadIdx.x;
    if (idx >= BB * HH * LL * NB) return;
    const int t = idx % NB;
    const int rest = idx / NB;
    const int q = rest % LL;
    const int bh = rest / LL;
    const int h = bh % HH;
    const int b = bh / HH;
    const float* qp = Qv + (b * LL + q) * DD + h * DHH;
    const float* rp = rel_table + t * DD + h * DHH;
    float a = 0.f;
#pragma unroll
    for (int d4 = 0; d4 < DHH; d4 += 4) {
        const float4 qq = *(const float4*)&qp[d4];
        const float4 rr = *(const float4*)&rp[d4];
        a = fmaf(qq.x, rr.x, fmaf(qq.y, rr.y, fmaf(qq.z, rr.z, fmaf(qq.w, rr.w, a))));
    }
    P[idx] = a;
}

// K3: scores + softmax. Block = (b, 16q, h), 512 thr = 8 waves; wave w owns q rows
// {2w, 2w+1}; thread covers k in {4l..4l+3, 4l+256..4l+259}. K float4-coalesced
// from KT; Q via LDS broadcast b128 (32/thread); per-row softmax is wave-local
// (no cross-wave handoff, one barrier total). Masked -> e = 0 exactly.
__global__ __launch_bounds__(512) void scores_kernel(const float* __restrict__ Qu,
    const float* __restrict__ KT, const float* __restrict__ P,
    const int* __restrict__ mask, const int* __restrict__ dist,
    float* __restrict__ attn) {
    __shared__ float Qs[16][DHH];
    __shared__ float Ps[16][NB];
    const int blk = blockIdx.x;         // ((b*32 + qt)*8 + h)
    const int h = blk & 7;
    const int rest = blk >> 3;
    const int qt = rest & 31;
    const int b = rest >> 5;
    const int q0 = qt * 16;
    const int t = threadIdx.x;
    const int w = t >> 6, l = t & 63;
    {
        const int r = t >> 5, c = t & 31;
        Qs[r][c] = Qu[(b * LL + q0 + r) * DD + h * DHH + c];
    }
    if (t < 16 * NB) {
        Ps[t / NB][t % NB] = P[((b * HH + h) * LL + q0 + t / NB) * NB + t % NB];
    }
    __syncthreads();

    const int r0 = 2 * w;               // local rows r0, r0+1
    const long kbase = (long)(b * HH + h) * DHH * LL;
    float e0[2][4], e1[2][4];
    float sum0 = 0.f, sum1 = 0.f;
#pragma unroll
    for (int s = 0; s < 2; ++s) {
        const int k0 = 4 * l + 256 * s;
        const int4 dx0 = *(const int4*)&dist[(b * LL + q0 + r0) * LL + k0];
        const int4 dx1 = *(const int4*)&dist[(b * LL + q0 + r0 + 1) * LL + k0];
        const int4 mx0 = *(const int4*)&mask[(b * LL + q0 + r0) * LL + k0];
        const int4 mx1 = *(const int4*)&mask[(b * LL + q0 + r0 + 1) * LL + k0];
        float s0[4], s1[4];
        s0[0] = Ps[r0][dx0.x]; s0[1] = Ps[r0][dx0.y]; s0[2] = Ps[r0][dx0.z]; s0[3] = Ps[r0][dx0.w];
        s1[0] = Ps[r0 + 1][dx1.x]; s1[1] = Ps[r0 + 1][dx1.y]; s1[2] = Ps[r0 + 1][dx1.z]; s1[3] = Ps[r0 + 1][dx1.w];
#pragma unroll
        for (int d4 = 0; d4 < DHH; d4 += 4) {
            const float4 q0v = *(const float4*)&Qs[r0][d4];
            const float4 q1v = *(const float4*)&Qs[r0 + 1][d4];
            float4 kv[4];
#pragma unroll
            for (int j = 0; j < 4; ++j)
                kv[j] = *(const float4*)&KT[kbase + (long)(d4 + j) * LL + k0];
            const float* qf0 = (const float*)&q0v;
            const float* qf1 = (const float*)&q1v;
#pragma unroll
            for (int j = 0; j < 4; ++j) {
                s0[0] = fmaf(qf0[j], kv[j].x, s0[0]);
                s0[1] = fmaf(qf0[j], kv[j].y, s0[1]);
                s0[2] = fmaf(qf0[j], kv[j].z, s0[2]);
                s0[3] = fmaf(qf0[j], kv[j].w, s0[3]);
                s1[0] = fmaf(qf1[j], kv[j].x, s1[0]);
                s1[1] = fmaf(qf1[j], kv[j].y, s1[1]);
                s1[2] = fmaf(qf1[j], kv[j].z, s1[2]);
                s1[3] = fmaf(qf1[j], kv[j].w, s1[3]);
            }
        }
        e0[s][0] = mx0.x ? 0.f : __expf(s0[0]);
        e0[s][1] = mx0.y ? 0.f : __expf(s0[1]);
        e0[s][2] = mx0.z ? 0.f : __expf(s0[2]);
        e0[s][3] = mx0.w ? 0.f : __expf(s0[3]);
        e1[s][0] = mx1.x ? 0.f : __expf(s1[0]);
        e1[s][1] = mx1.y ? 0.f : __expf(s1[1]);
        e1[s][2] = mx1.z ? 0.f : __expf(s1[2]);
        e1[s][3] = mx1.w ? 0.f : __expf(s1[3]);
        sum0 += (e0[s][0] + e0[s][1]) + (e0[s][2] + e0[s][3]);
        sum1 += (e1[s][0] + e1[s][1]) + (e1[s][2] + e1[s][3]);
    }
    for (int off = 32; off > 0; off >>= 1) {
        sum0 += __shfl_xor(sum0, off);
        sum1 += __shfl_xor(sum1, off);
    }
    const float i0 = 1.0f / sum0, i1 = 1.0f / sum1;
    float* a0 = attn + ((long)(b * HH + h) * LL + q0 + r0) * LL;
    float* a1 = a0 + LL;
#pragma unroll
    for (int s = 0; s < 2; ++s) {
        const int k0 = 4 * l + 256 * s;
        *(float4*)&a0[k0] = make_float4(e0[s][0] * i0, e0[s][1] * i0, e0[s][2] * i0, e0[s][3] * i0);
        *(float4*)&a1[k0] = make_float4(e1[s][0] * i1, e1[s][1] * i1, e1[s][2] * i1, e1[s][3] * i1);
    }
}

// K4: fused ctx + out projection. Block = (b, 4q), thread = d (V read once/block,
// coalesced). Explicit A/B register pipeline (chunk = 8 k) for memory-level
// parallelism: ~32 loads in flight per wave.
__global__ __launch_bounds__(256) void ctx_out_kernel(const float* __restrict__ attn,
    const float* __restrict__ V, const float* __restrict__ Wo,
    const float* __restrict__ bo, float* __restrict__ out) {
    __shared__ float Cs[4][DD];
    const int blk = blockIdx.x;          // b*128 + qt
    const int b = blk >> 7;
    const int q0 = (blk & 127) * 4;
    const int d = threadIdx.x;
    const int h = d >> 5;
    const float* vb = V + b * LL * DD + d;
    const float* ab = attn + ((long)(b * HH + h) * LL + q0) * LL;
    float acc[4][2] = {{0.f,0.f},{0.f,0.f},{0.f,0.f},{0.f,0.f}};
    float vA[8], vB[8];
    float4 pA[4][2], pB[4][2];
#pragma unroll
    for (int j = 0; j < 8; ++j) vA[j] = vb[j * DD];
#pragma unroll
    for (int q = 0; q < 4; ++q) {
        pA[q][0] = *(const float4*)&ab[q * LL];
        pA[q][1] = *(const float4*)&ab[q * LL + 4];
    }
    for (int k0 = 0; k0 < LL; k0 += 16) {
        // prefetch chunk k0+8 into B
#pragma unroll
        for (int j = 0; j < 8; ++j) vB[j] = vb[(k0 + 8 + j) * DD];
#pragma unroll
        for (int q = 0; q < 4; ++q) {
            pB[q][0] = *(const float4*)&ab[q * LL + k0 + 8];
            pB[q][1] = *(const float4*)&ab[q * LL + k0 + 12];
        }
        // compute A
#pragma unroll
        for (int q = 0; q < 4; ++q) {
            acc[q][0] = fmaf(pA[q][0].x, vA[0], fmaf(pA[q][0].y, vA[1],
                        fmaf(pA[q][0].z, vA[2], fmaf(pA[q][0].w, vA[3], acc[q][0]))));
            acc[q][1] = fmaf(pA[q][1].x, vA[4], fmaf(pA[q][1].y, vA[5],
                        fmaf(pA[q][1].z, vA[6], fmaf(pA[q][1].w, vA[7], acc[q][1]))));
        }
        // prefetch chunk k0+16 into A (guarded)
        if (k0 + 16 < LL) {
#pragma unroll
            for (int j = 0; j < 8; ++j) vA[j] = vb[(k0 + 16 + j) * DD];
#pragma unroll
            for (int q = 0; q < 4; ++q) {
                pA[q][0] = *(const float4*)&ab[q * LL + k0 + 16];
                pA[q][1] = *(const float4*)&ab[q * LL + k0 + 20];
            }
        }
        // compute B
#pragma unroll
        for (int q = 0; q < 4; ++q) {
            acc[q][0] = fmaf(pB[q][0].x, vB[0], fmaf(pB[q][0].y, vB[1],
                        fmaf(pB[q][0].z, vB[2], fmaf(pB[q][0].w, vB[3], acc[q][0]))));
            acc[q][1] = fmaf(pB[q][1].x, vB[4], fmaf(pB[q][1].y, vB[5],
                        fmaf(pB[q][1].z, vB[6], fmaf(pB[q][1].w, vB[7], acc[q][1]))));
        }
    }
#pragma unroll
    for (int q = 0; q < 4; ++q) Cs[q][d] = acc[q][0] + acc[q][1];
    __syncthreads();
    float o[4];
#pragma unroll
    for (int q = 0; q < 4; ++q) o[q] = bo[d];
    for (int i0 = 0; i0 < DD; i0 += 8) {
        float wv[8];
#pragma unroll
        for (int j = 0; j < 8; ++j) wv[j] = Wo[(i0 + j) * DD + d];
#pragma unroll
        for (int q = 0; q < 4; ++q) {
            const float4 cA = *(const float4*)&Cs[q][i0];
            const float4 cB = *(const float4*)&Cs[q][i0 + 4];
            o[q] = fmaf(cA.x, wv[0], fmaf(cA.y, wv[1], fmaf(cA.z, wv[2], fmaf(cA.w, wv[3], o[q]))));
            o[q] = fmaf(cB.x, wv[4], fmaf(cB.y, wv[5], fmaf(cB.z, wv[6], fmaf(cB.w, wv[7], o[q]))));
        }
    }
#pragma unroll
    for (int q = 0; q < 4; ++q) out[(b * LL + q0 + q) * DD + d] = o[q];
}

extern "C" void kernel_launch(void* const* d_in, const int* in_sizes, int n_in,
                              void* d_out, int out_size, void* d_ws, size_t ws_size,
                              hipStream_t stream) {
    const float* x    = (const float*)d_in[0];
    const int* mk     = (const int*)d_in[1];   // jax bool -> int32
    const int* dist   = (const int*)d_in[2];
    const float* Wq = (const float*)d_in[3];
    const float* bq = (const float*)d_in[4];
    const float* Wk = (const float*)d_in[5];
    const float* bk = (const float*)d_in[6];
    const float* Wv = (const float*)d_in[7];
    const float* bv = (const float*)d_in[8];
    const float* Wo = (const float*)d_in[9];
    const float* bo = (const float*)d_in[10];
    const float* rel_table = (const float*)d_in[11];
    const float* uvec = (const float*)d_in[12];
    const float* vvec = (const float*)d_in[13];

    float* out  = (float*)d_out;                 // (B,L,D)
    float* attn = out + BB * LL * DD;            // (B,H,L,L)

    float* Qu = (float*)d_ws;                    // q/sqrt(dh) + u
    float* Qv = Qu + BB * LL * DD;               // q/sqrt(dh) + v
    float* KT = Qv + BB * LL * DD;               // [B][H][DH][L]
    float* V  = KT + BB * LL * DD;               // [B][L][D]
    float* P  = V + BB * LL * DD;                // [B][H][L][NB]; 9.18 MB total

    qkv_kernel<<<3 * 256, 256, 0, stream>>>(x, Wq, bq, Wk, bk, Wv, bv, uvec, vvec,
                                            Qu, Qv, KT, V);
    relp_kernel<<<(BB * HH * LL * NB + 255) / 256, 256, 0, stream>>>(Qv, rel_table, P);
    scores_kernel<<<BB * (LL / 16) * HH, 512, 0, stream>>>(Qu, KT, P, mk, dist, attn);
    ctx_out_kernel<<<BB * (LL / 4), 256, 0, stream>>>(attn, V, Wo, bo, out);
}